// Round 6
// baseline (444.667 us; speedup 1.0000x reference)
//
#include <hip/hip_runtime.h>
#include <cstddef>
#include <cstdint>

// Problem: B=2, S=2048, E=1024, H=16, D=64.  Softmax over HEADS (ref quirk).
#define BATCH 2
#define S_LEN 2048
#define E_DIM 1024
#define NH    16
#define HD    64
#define M_ROWS (BATCH * S_LEN)   // 4096

// fold softmax scale into Q at projection time: 1/sqrt(64) * log2(e)
#define QSCALE 0.18033688011112042f

typedef unsigned short u16;
typedef short     bf16x8 __attribute__((ext_vector_type(8)));
typedef _Float16  f16x8  __attribute__((ext_vector_type(8)));
typedef __fp16    h16x2  __attribute__((ext_vector_type(2)));   // cvt_pkrtz return type
typedef float     f32x4  __attribute__((ext_vector_type(4)));

__device__ __forceinline__ u16 f2bf(float f) {
    union { float f; unsigned u; } v; v.f = f;
    unsigned r = v.u + 0x7fffu + ((v.u >> 16) & 1u);   // RNE
    return (u16)(r >> 16);
}
__device__ __forceinline__ float bf2f(u16 h) {
    union { unsigned u; float f; } v; v.u = ((unsigned)h) << 16;
    return v.f;
}

// async global->LDS DMA, 16 B per lane (global_load_lds_dwordx4).
__device__ __forceinline__ void load_lds16(const u16* g, u16* l) {
    __builtin_amdgcn_global_load_lds(
        (const __attribute__((address_space(1))) unsigned int*)g,
        (__attribute__((address_space(3))) unsigned int*)l, 16, 0, 0);
}

// ---------------------------------------------------------------------------
// fp32 -> bf16 bulk convert (n % 4 == 0)
// ---------------------------------------------------------------------------
__global__ void cvt_bf16(const float* __restrict__ in, u16* __restrict__ out, int n)
{
    int i = (blockIdx.x * 256 + threadIdx.x) * 4;
    if (i + 3 < n) {
        float4 v = *(const float4*)(in + i);
        u16 o[4] = { f2bf(v.x), f2bf(v.y), f2bf(v.z), f2bf(v.w) };
        *(uint2*)(out + i) = *(const uint2*)o;
    }
}

// ---------------------------------------------------------------------------
// ctx = a + b  (bf16 in, fp32 add, bf16 out)
// ---------------------------------------------------------------------------
__global__ void combine_ctx(const u16* __restrict__ a, const u16* __restrict__ b,
                            u16* __restrict__ c, int n)
{
    int i = (blockIdx.x * 256 + threadIdx.x) * 4;
    if (i + 3 < n) {
        uint2 ua = *(const uint2*)(a + i);
        uint2 ub = *(const uint2*)(b + i);
        const u16* pa = (const u16*)&ua; const u16* pb = (const u16*)&ub;
        u16 o[4];
#pragma unroll
        for (int j = 0; j < 4; ++j) o[j] = f2bf(bf2f(pa[j]) + bf2f(pb[j]));
        *(uint2*)(c + i) = *(const uint2*)o;
    }
}

// ---------------------------------------------------------------------------
// Fused QKV projection GEMM (m97-style DMA staging).
//   seg 0 -> Q, bf16, PRE-SCALED by QSCALE (softmax scale folded in)
//   seg 1 -> K, bf16
//   seg 2 -> V, written TRANSPOSED Vt[b][e][s] in FP16 (PV runs fp16 MFMA)
// ---------------------------------------------------------------------------
__global__ __launch_bounds__(256)
void gemm_qkv(const u16* __restrict__ A, const u16* __restrict__ W3,
              const float* __restrict__ bq, const float* __restrict__ bk,
              const float* __restrict__ bv,
              u16* __restrict__ Qb, u16* __restrict__ Kb, u16* __restrict__ Vtb)
{
    __shared__ u16 Al[128 * 32];
    __shared__ u16 Bl[128 * 32];
    const int K = E_DIM;
    const int t = threadIdx.x;
    const int w = t >> 6, lane = t & 63;
    const int quad = lane >> 4, lm = lane & 15;
    const int wy = w >> 1, wx = w & 1;
    const int m0 = blockIdx.x * 128, n0 = blockIdx.y * 128;
    const int lrow  = lane >> 2;
    const int lcol8 = (lane & 3) * 8;

    f32x4 acc[4][4] = {};

    for (int kb = 0; kb < K; kb += 32) {
        __syncthreads();
#pragma unroll
        for (int i = 0; i < 2; ++i) {
            const int r0 = w * 32 + i * 16;
            load_lds16(A  + (size_t)(m0 + r0 + lrow) * K + kb + lcol8, &Al[r0 * 32]);
            load_lds16(W3 + (size_t)(n0 + r0 + lrow) * K + kb + lcol8, &Bl[r0 * 32]);
        }
        __syncthreads();

        bf16x8 af[4], bfr[4];
#pragma unroll
        for (int i = 0; i < 4; ++i)
            af[i] = *(const bf16x8*)(Al + (wy * 64 + i * 16 + lm) * 32 + quad * 8);
#pragma unroll
        for (int j = 0; j < 4; ++j)
            bfr[j] = *(const bf16x8*)(Bl + (wx * 64 + j * 16 + lm) * 32 + quad * 8);
#pragma unroll
        for (int i = 0; i < 4; ++i)
#pragma unroll
            for (int j = 0; j < 4; ++j)
                acc[i][j] = __builtin_amdgcn_mfma_f32_16x16x32_bf16(af[i], bfr[j], acc[i][j], 0, 0, 0);
    }

    const int seg = n0 >> 10;            // 0=Q, 1=K, 2=V
    const int nl0 = n0 & 1023;
    const float* bs = (seg == 0) ? bq : (seg == 1) ? bk : bv;

    if (seg < 2) {
        u16* dst = (seg == 0) ? Qb : Kb;
        const float scl = (seg == 0) ? QSCALE : 1.0f;
#pragma unroll
        for (int j = 0; j < 4; ++j) {
            const int n = nl0 + wx * 64 + j * 16 + lm;
            const float bias = bs[n];
#pragma unroll
            for (int i = 0; i < 4; ++i) {
                const int mrow = m0 + wy * 64 + i * 16 + quad * 4;
#pragma unroll
                for (int rg = 0; rg < 4; ++rg)
                    dst[(size_t)(mrow + rg) * E_DIM + n] = f2bf((acc[i][j][rg] + bias) * scl);
            }
        }
    } else {
        // V: fp16, transposed -> Vt[b][e][s]
#pragma unroll
        for (int j = 0; j < 4; ++j) {
            const int n = nl0 + wx * 64 + j * 16 + lm;
            const float bias = bs[n];
#pragma unroll
            for (int i = 0; i < 4; ++i) {
                const int mrow = m0 + wy * 64 + i * 16 + quad * 4;
                const int batch = mrow >> 11;
                const int sloc  = mrow & 2047;
                u16 o[4];
#pragma unroll
                for (int rg = 0; rg < 4; ++rg) {
                    union { _Float16 h; u16 u; } cv;
                    cv.h = (_Float16)(acc[i][j][rg] + bias);
                    o[rg] = cv.u;
                }
                *(uint2*)&Vtb[(size_t)batch * E_DIM * S_LEN + (size_t)n * S_LEN + sloc]
                    = *(const uint2*)o;
            }
        }
    }
}

// ---------------------------------------------------------------------------
// Output projection GEMM — unchanged.
// ---------------------------------------------------------------------------
__global__ __launch_bounds__(256)
void gemm_wo(const u16* __restrict__ A, const u16* __restrict__ B,
             const float* __restrict__ bias, float* __restrict__ C)
{
    __shared__ u16 Al[128 * 32];
    __shared__ u16 Bl[128 * 32];
    const int K = E_DIM, N = E_DIM;
    const int t = threadIdx.x;
    const int w = t >> 6, lane = t & 63;
    const int quad = lane >> 4, lm = lane & 15;
    const int wy = w >> 1, wx = w & 1;
    const int m0 = blockIdx.x * 128, n0 = blockIdx.y * 128;
    const int lrow  = lane >> 2;
    const int lcol8 = (lane & 3) * 8;

    f32x4 acc[4][4] = {};

    for (int kb = 0; kb < K; kb += 32) {
        __syncthreads();
#pragma unroll
        for (int i = 0; i < 2; ++i) {
            const int r0 = w * 32 + i * 16;
            load_lds16(A + (size_t)(m0 + r0 + lrow) * K + kb + lcol8, &Al[r0 * 32]);
            load_lds16(B + (size_t)(n0 + r0 + lrow) * K + kb + lcol8, &Bl[r0 * 32]);
        }
        __syncthreads();

        bf16x8 af[4], bfr[4];
#pragma unroll
        for (int i = 0; i < 4; ++i)
            af[i] = *(const bf16x8*)(Al + (wy * 64 + i * 16 + lm) * 32 + quad * 8);
#pragma unroll
        for (int j = 0; j < 4; ++j)
            bfr[j] = *(const bf16x8*)(Bl + (wx * 64 + j * 16 + lm) * 32 + quad * 8);
#pragma unroll
        for (int i = 0; i < 4; ++i)
#pragma unroll
            for (int j = 0; j < 4; ++j)
                acc[i][j] = __builtin_amdgcn_mfma_f32_16x16x32_bf16(af[i], bfr[j], acc[i][j], 0, 0, 0);
    }

#pragma unroll
    for (int j = 0; j < 4; ++j) {
        const int n = n0 + wx * 64 + j * 16 + lm;
        const float bs = bias[n];
#pragma unroll
        for (int i = 0; i < 4; ++i) {
            const int mrow = m0 + wy * 64 + i * 16 + quad * 4;
#pragma unroll
            for (int rg = 0; rg < 4; ++rg)
                C[(size_t)(mrow + rg) * N + n] = acc[i][j][rg] + bs;
        }
    }
}

// ---------------------------------------------------------------------------
// attn_v8: wave-local softmax.  Each wave computes ALL 16 heads for ITS OWN
// 16 k-rows per chunk (k = k0 + w*16 + lm), so MFMA output D[row=k][col=q]
// puts the full 16-head score vector for each (k,q) in ONE thread:
//   sacc[h][rg] = S[h][k = k0+w*16+quad*4+rg][q = q0+lm]
// -> softmax over heads is 100% register-local.  No S exchange, no barriers
// for it.  Only P crosses waves (PV needs all k for a wave's 4 PV-heads):
// one b64 LDS write per head -> BAR_A -> b128 reads.  2 barriers per 64-k
// chunk (v7 had 4 per 64k + full S4 round-trip).
//   LDS: Ql [16 q][1032] bf16 (Q tile staged once; pad -> conflict-free
//        reads), P5 [16 h][16 q][72] fp16 (pad 72: 2-way-ish on writes,
//        uniform b128 reads).  69.9 KB total; epilogue Ol overlays.
//   VGPR: in-place exp (sacc reused as P), V prefetch split in 2 windows;
//        peak ~220, statically indexed, no helper fns (R4 spill lesson).
// ---------------------------------------------------------------------------
__global__ __launch_bounds__(256, 2)
void attn_v8(const u16* __restrict__ Q, const u16* __restrict__ K,
             const u16* __restrict__ Vt, u16* __restrict__ ctxA,
             u16* __restrict__ ctxB)
{
    __shared__ __align__(16) u16 smem[34944];    // 69888 B
    u16* Ql = smem;                  // [16][1032] bf16 = 33024 B
    u16* P5 = smem + 16 * 1032;      // [16][16][72] fp16 = 36864 B

    const int t     = threadIdx.x;
    const int w     = t >> 6, lane = t & 63;
    const int quad  = lane >> 4, lm = lane & 15;

    // XCD-aware decode (kept from v7: FETCH 41.6 -> 30.5 MB)
    const int i     = blockIdx.x;
    const int xcd   = i & 7;
    const int slot  = i >> 3;
    const int combo = xcd >> 1;
    const int b     = combo >> 1;
    const int khalf = combo & 1;
    const int qt    = ((xcd & 1) << 6) | slot;
    const int q0    = qt * 16;

    const size_t qbase = ((size_t)b * S_LEN + q0) * E_DIM;
    const size_t kmat  = (size_t)b * S_LEN * E_DIM;
    const size_t vtb   = (size_t)b * E_DIM * S_LEN;

    // ---- stage Q tile [16 q][1024] into LDS with pitch 1032 ----
    {
        const int r = t >> 4, cb = (t & 15) * 64;
#pragma unroll
        for (int j = 0; j < 8; ++j)
            *(uint4*)(Ql + r * 1032 + cb + j * 8) =
                *(const uint4*)(Q + qbase + (size_t)r * E_DIM + cb + j * 8);
    }
    __syncthreads();

    f32x4 oacc[4][4] = {};           // [h2][dt] for PV heads hPV..hPV+3
    const int kbeg = khalf * (S_LEN / 2);
    const int hPV  = w * 4;

    for (int c = 0; c < (S_LEN / 2) / 64; ++c) {   // 16 chunks of 64 k
        const int k0 = kbeg + c * 64;
        const size_t krow = kmat + (size_t)(k0 + w * 16 + lm) * E_DIM;

        // ---- QK^T: all 16 heads, this wave's 16 k-rows ----
        f32x4 sacc[16];
#pragma unroll
        for (int h = 0; h < 16; ++h) {
            bf16x8 kf0 = *(const bf16x8*)(K + krow + h * 64 + quad * 8);
            bf16x8 kf1 = *(const bf16x8*)(K + krow + h * 64 + 32 + quad * 8);
            bf16x8 qf0 = *(const bf16x8*)(Ql + lm * 1032 + h * 64 + quad * 8);
            bf16x8 qf1 = *(const bf16x8*)(Ql + lm * 1032 + h * 64 + 32 + quad * 8);
            f32x4 sf = {};
            sf = __builtin_amdgcn_mfma_f32_16x16x32_bf16(kf0, qf0, sf, 0, 0, 0);
            sf = __builtin_amdgcn_mfma_f32_16x16x32_bf16(kf1, qf1, sf, 0, 0, 0);
            sacc[h] = sf;
        }

        // ---- V prefetch window 0 (k0..k0+31); hides under softmax ----
        f16x8 vfA[4][4];
#pragma unroll
        for (int h2 = 0; h2 < 4; ++h2)
#pragma unroll
            for (int dt = 0; dt < 4; ++dt)
                vfA[h2][dt] = *(const f16x8*)(Vt + vtb
                              + (size_t)((hPV + h2) * 64 + dt * 16 + lm) * S_LEN
                              + k0 + quad * 8);

        // ---- register softmax over heads: 4 (k,q) pairs, in place ----
#pragma unroll
        for (int rg = 0; rg < 4; ++rg) {
            float m = sacc[0][rg];
#pragma unroll
            for (int h = 1; h < 16; ++h) m = fmaxf(m, sacc[h][rg]);
            float sum = 0.f;
#pragma unroll
            for (int h = 0; h < 16; ++h) {
                const float e = __builtin_amdgcn_exp2f(sacc[h][rg] - m);
                sacc[h][rg] = e; sum += e;
            }
            const float inv = __builtin_amdgcn_rcpf(sum);
#pragma unroll
            for (int h = 0; h < 16; ++h) sacc[h][rg] *= inv;
        }

        // ---- pack 4 fp16 per head -> one b64 LDS write each ----
#pragma unroll
        for (int h = 0; h < 16; ++h) {
            union { h16x2 v; unsigned u; } c0, c1;
            c0.v = __builtin_amdgcn_cvt_pkrtz(sacc[h][0], sacc[h][1]);
            c1.v = __builtin_amdgcn_cvt_pkrtz(sacc[h][2], sacc[h][3]);
            uint2 pk; pk.x = c0.u; pk.y = c1.u;
            *(uint2*)(P5 + (size_t)h * 1152 + lm * 72 + w * 16 + quad * 4) = pk;
        }

        asm volatile("s_waitcnt lgkmcnt(0)" ::: "memory");
        __builtin_amdgcn_s_barrier();   // BAR_A: P5 complete across waves

        // ---- V prefetch window 1 (k0+32..k0+63) ----
        f16x8 vfB[4][4];
#pragma unroll
        for (int h2 = 0; h2 < 4; ++h2)
#pragma unroll
            for (int dt = 0; dt < 4; ++dt)
                vfB[h2][dt] = *(const f16x8*)(Vt + vtb
                              + (size_t)((hPV + h2) * 64 + dt * 16 + lm) * S_LEN
                              + k0 + 32 + quad * 8);

        // ---- PV: 2 k-windows x 4 heads x 4 dt ----
#pragma unroll
        for (int h2 = 0; h2 < 4; ++h2) {
            f16x8 pa0 = *(const f16x8*)(P5 + (size_t)(hPV + h2) * 1152
                                        + lm * 72 + quad * 8);
#pragma unroll
            for (int dt = 0; dt < 4; ++dt)
                oacc[h2][dt] = __builtin_amdgcn_mfma_f32_16x16x32_f16(pa0, vfA[h2][dt],
                                                                      oacc[h2][dt], 0, 0, 0);
        }
#pragma unroll
        for (int h2 = 0; h2 < 4; ++h2) {
            f16x8 pa1 = *(const f16x8*)(P5 + (size_t)(hPV + h2) * 1152
                                        + lm * 72 + 32 + quad * 8);
#pragma unroll
            for (int dt = 0; dt < 4; ++dt)
                oacc[h2][dt] = __builtin_amdgcn_mfma_f32_16x16x32_f16(pa1, vfB[h2][dt],
                                                                      oacc[h2][dt], 0, 0, 0);
        }

        asm volatile("s_waitcnt lgkmcnt(0)" ::: "memory");
        __builtin_amdgcn_s_barrier();   // BAR_B: all P5 reads retired before next writes
    }

    __syncthreads();
    u16* Ol = smem;          // [16 q][1024 e] = 32768 B <= 69888 B
#pragma unroll
    for (int h2 = 0; h2 < 4; ++h2) {
        const int h = hPV + h2;
#pragma unroll
        for (int dt = 0; dt < 4; ++dt)
#pragma unroll
            for (int rg = 0; rg < 4; ++rg)
                Ol[(quad * 4 + rg) * 1024 + h * 64 + dt * 16 + lm] = f2bf(oacc[h2][dt][rg]);
    }
    __syncthreads();
    u16* dst = khalf ? ctxB : ctxA;
#pragma unroll
    for (int i2 = 0; i2 < 8; ++i2) {
        const int unit = i2 * 256 + t;
        const int r = unit >> 7, cu = unit & 127;
        *(bf16x8*)(dst + ((size_t)b * S_LEN + q0 + r) * E_DIM + cu * 8) =
            *(const bf16x8*)(Ol + r * 1024 + cu * 8);
    }
}

// ---------------------------------------------------------------------------
extern "C" void kernel_launch(void* const* d_in, const int* in_sizes, int n_in,
                              void* d_out, int out_size, void* d_ws, size_t ws_size,
                              hipStream_t stream)
{
    const float* x  = (const float*)d_in[0];
    const float* Wq = (const float*)d_in[1];
    const float* bq = (const float*)d_in[2];
    const float* Wk = (const float*)d_in[3];
    const float* bk = (const float*)d_in[4];
    const float* Wv = (const float*)d_in[5];
    const float* bv = (const float*)d_in[6];
    const float* Wo = (const float*)d_in[7];
    const float* bo = (const float*)d_in[8];
    float* out = (float*)d_out;

    // bf16/fp16 workspace (u16 elems), 56 MB:
    const size_t MAT = (size_t)M_ROWS * E_DIM;   // 4M elems
    const size_t WSZ = (size_t)E_DIM * E_DIM;    // 1M elems
    u16* xb   = (u16*)d_ws;          // x; later combined ctx
    u16* W3   = xb   + MAT;          // Wq|Wk|Wv concat [3072][1024]
    u16* Wob  = W3   + 3 * WSZ;
    u16* Qb   = Wob  + WSZ;
    u16* Kb   = Qb   + MAT;
    u16* Vtb  = Kb   + MAT;          // V transposed [b][e][s], FP16
    u16* ctxA = Vtb  + MAT;
    u16* ctxB = ctxA + MAT;

    // 1) convert inputs to bf16 (weights into concat buffer)
    cvt_bf16<<<(int)(MAT / 1024), 256, 0, stream>>>(x,  xb, (int)MAT);
    cvt_bf16<<<(int)(WSZ / 1024), 256, 0, stream>>>(Wq, W3,           (int)WSZ);
    cvt_bf16<<<(int)(WSZ / 1024), 256, 0, stream>>>(Wk, W3 + WSZ,     (int)WSZ);
    cvt_bf16<<<(int)(WSZ / 1024), 256, 0, stream>>>(Wv, W3 + 2 * WSZ, (int)WSZ);
    cvt_bf16<<<(int)(WSZ / 1024), 256, 0, stream>>>(Wo, Wob,          (int)WSZ);

    // 2) fused QKV projection (Q pre-scaled, V fp16-transposed)
    dim3 qkvgrid(M_ROWS / 128, 3 * E_DIM / 128);   // 32 x 24 = 768 blocks
    gemm_qkv<<<qkvgrid, 256, 0, stream>>>(xb, W3, bq, bk, bv, Qb, Kb, Vtb);

    // 3) fused MFMA attention (wave-local softmax over heads), KSPLIT=2
    attn_v8<<<BATCH * 128 * 2, 256, 0, stream>>>(Qb, Kb, Vtb, ctxA, ctxB);

    // 4) combine k-halves into xb (x is dead)
    combine_ctx<<<(int)(MAT / 1024), 256, 0, stream>>>(ctxA, ctxB, xb, (int)MAT);

    // 5) output projection (fp32 out)
    dim3 ogrid(M_ROWS / 128, E_DIM / 128);         // 32 x 8
    gemm_wo<<<ogrid, 256, 0, stream>>>(xb, Wob, bo, out);
}